// Round 1
// baseline (1356.157 us; speedup 1.0000x reference)
//
#include <hip/hip_runtime.h>

#define N_NODES 100000
#define N_EDGES 1600000
#define N_GRAPHS 1024
#define D 128
#define NL 3
#define BN_EPS 1e-5f

// ---------------- dtype-robust index accessor ----------------
// flag==1: indices are int64 (little-endian, values < 2^31) ; flag==0: int32
__device__ __forceinline__ int geti(const void* p, long long i, int f64) {
    return f64 ? (int)((const long long*)p)[i] : ((const int*)p)[i];
}

__global__ void k_detect(const void* ei, int* flag) {
    // If int64 layout, the high 32-bit word of each index (odd int32 position) is 0.
    const int* p = (const int*)ei;
    int acc = 0;
    for (int i = 0; i < 128; ++i) acc |= p[2 * i + 1];
    *flag = (acc == 0) ? 1 : 0;
}

// ---------------- CSR build ----------------
__global__ void k_hist(const void* ei, const int* __restrict__ flag, int* __restrict__ deg) {
    int e = blockIdx.x * 256 + threadIdx.x;
    int f = *flag;
    if (e < N_EDGES) {
        int d = geti(ei, (long long)N_EDGES + e, f);
        atomicAdd(&deg[d], 1);
    }
}

__global__ void k_scan(const int* __restrict__ deg, int* __restrict__ rowp,
                       int* __restrict__ cursor) {
    __shared__ int sdata[1024];
    int tid = threadIdx.x;
    const int CH = (N_NODES + 1023) / 1024; // 98
    int start = tid * CH;
    int end = min(start + CH, N_NODES);
    if (start > N_NODES) start = N_NODES;
    int sum = 0;
    for (int i = start; i < end; ++i) sum += deg[i];
    sdata[tid] = sum;
    __syncthreads();
    for (int off = 1; off < 1024; off <<= 1) {
        int v = (tid >= off) ? sdata[tid - off] : 0;
        __syncthreads();
        sdata[tid] += v;
        __syncthreads();
    }
    int base = (tid == 0) ? 0 : sdata[tid - 1];
    for (int i = start; i < end; ++i) {
        rowp[i] = base;
        cursor[i] = base;
        base += deg[i];
    }
    if (tid == 1023) rowp[N_NODES] = sdata[1023];
}

__global__ void k_scatter(const void* ei, const int* __restrict__ flag,
                          int* __restrict__ cursor, int* __restrict__ eidx) {
    int e = blockIdx.x * 256 + threadIdx.x;
    int f = *flag;
    if (e < N_EDGES) {
        int s = geti(ei, e, f);
        int d = geti(ei, (long long)N_EDGES + e, f);
        int pos = atomicAdd(&cursor[d], 1);
        eidx[pos] = s;
    }
}

// ---------------- aggregation: out[i] = x[i] + sum_{j in N(i)} x[j] ----------------
__global__ void k_agg(const float* __restrict__ xin, const int* __restrict__ rowp,
                      const int* __restrict__ eidx, float* __restrict__ out) {
    int wid = threadIdx.x >> 6;
    int lane = threadIdx.x & 63;
    int node = blockIdx.x * 4 + wid;
    const float2* x2 = (const float2*)xin;
    float2 acc = x2[(size_t)node * 64 + lane];
    int s = rowp[node], e = rowp[node + 1];
    int i = s;
    for (; i + 1 < e; i += 2) {
        int j0 = eidx[i], j1 = eidx[i + 1];
        float2 v0 = x2[(size_t)j0 * 64 + lane];
        float2 v1 = x2[(size_t)j1 * 64 + lane];
        acc.x += v0.x + v1.x;
        acc.y += v0.y + v1.y;
    }
    if (i < e) {
        int j0 = eidx[i];
        float2 v0 = x2[(size_t)j0 * 64 + lane];
        acc.x += v0.x;
        acc.y += v0.y;
    }
    ((float2*)out)[(size_t)node * 64 + lane] = acc;
}

// ---------------- GEMM: out[M x 128] = A[M x 128] @ W[128 x 128] + bias ----------------
// MODE 1: plain load; epilogue stores z and accumulates per-feature sum/sumsq -> stats
// MODE 2: A-load applies BN (scale/shift) + ReLU; epilogue applies ReLU
template <int MODE>
__global__ __launch_bounds__(256) void k_lin(const float* __restrict__ A,
                                             const float* __restrict__ W,
                                             const float* __restrict__ bias,
                                             const float* __restrict__ ss,
                                             float* __restrict__ out,
                                             float* __restrict__ stats) {
    __shared__ float As[256][36];   // 256 rows x 32 k (pad to 36)
    __shared__ float Ws[32][128];
    __shared__ float ssum[128];
    __shared__ float ssq[128];

    int tid = threadIdx.x;
    int tx = tid & 15;   // col group
    int ty = tid >> 4;   // row group
    int row0 = blockIdx.x * 256;

    float acc[16][8];
#pragma unroll
    for (int i = 0; i < 16; ++i)
#pragma unroll
        for (int j = 0; j < 8; ++j) acc[i][j] = 0.f;

    int lrow = tid >> 3;        // 0..31
    int lk = (tid & 7) * 4;     // 0..28
    int wk = tid >> 5;          // 0..7
    int wc = (tid & 31) * 4;    // 0..124

    for (int kb = 0; kb < 128; kb += 32) {
        // stage A tile (256 x 32)
        float4 sc4, sh4;
        if (MODE == 2) {
            sc4 = *(const float4*)&ss[kb + lk];
            sh4 = *(const float4*)&ss[128 + kb + lk];
        }
#pragma unroll
        for (int p = 0; p < 8; ++p) {
            int r = lrow + 32 * p;
            int gr = row0 + r;
            float4 v = make_float4(0.f, 0.f, 0.f, 0.f);
            if (gr < N_NODES) v = *(const float4*)&A[(size_t)gr * 128 + kb + lk];
            if (MODE == 2) {
                v.x = fmaxf(v.x * sc4.x + sh4.x, 0.f);
                v.y = fmaxf(v.y * sc4.y + sh4.y, 0.f);
                v.z = fmaxf(v.z * sc4.z + sh4.z, 0.f);
                v.w = fmaxf(v.w * sc4.w + sh4.w, 0.f);
            }
            *(float4*)&As[r][lk] = v;
        }
        // stage W tile (32 x 128)
#pragma unroll
        for (int p = 0; p < 4; ++p) {
            int k = wk + 8 * p;
            *(float4*)&Ws[k][wc] = *(const float4*)&W[(size_t)(kb + k) * 128 + wc];
        }
        __syncthreads();

#pragma unroll 4
        for (int k = 0; k < 32; ++k) {
            float a[16], b[8];
#pragma unroll
            for (int i = 0; i < 16; ++i) a[i] = As[ty + 16 * i][k];
#pragma unroll
            for (int j = 0; j < 8; ++j) b[j] = Ws[k][tx + 16 * j];
#pragma unroll
            for (int i = 0; i < 16; ++i)
#pragma unroll
                for (int j = 0; j < 8; ++j) acc[i][j] += a[i] * b[j];
        }
        __syncthreads();
    }

    float bsv[8];
#pragma unroll
    for (int j = 0; j < 8; ++j) bsv[j] = bias[tx + 16 * j];

    if (MODE == 1) {
        if (tid < 128) { ssum[tid] = 0.f; ssq[tid] = 0.f; }
        __syncthreads();
    }

    float psum[8], psq[8];
#pragma unroll
    for (int j = 0; j < 8; ++j) { psum[j] = 0.f; psq[j] = 0.f; }

#pragma unroll
    for (int i = 0; i < 16; ++i) {
        int gr = row0 + ty + 16 * i;
        if (gr < N_NODES) {
#pragma unroll
            for (int j = 0; j < 8; ++j) {
                float z = acc[i][j] + bsv[j];
                if (MODE == 2) z = fmaxf(z, 0.f);
                out[(size_t)gr * 128 + tx + 16 * j] = z;
                if (MODE == 1) {
                    psum[j] += z;
                    psq[j] += z * z;
                }
            }
        }
    }

    if (MODE == 1) {
#pragma unroll
        for (int j = 0; j < 8; ++j) {
            atomicAdd(&ssum[tx + 16 * j], psum[j]);
            atomicAdd(&ssq[tx + 16 * j], psq[j]);
        }
        __syncthreads();
        if (tid < 128) {
            atomicAdd(&stats[tid], ssum[tid]);
            atomicAdd(&stats[128 + tid], ssq[tid]);
        }
    }
}

// ---------------- BN finalize: scale/shift per feature ----------------
__global__ void k_bnfin(const float* __restrict__ stats, const float* __restrict__ gamma,
                        const float* __restrict__ beta, float* __restrict__ ss) {
    int f = threadIdx.x;
    float s1 = stats[f];
    float s2 = stats[128 + f];
    float mu = s1 / (float)N_NODES;
    float var = s2 / (float)N_NODES - mu * mu;
    float rs = rsqrtf(var + BN_EPS);
    float sc = rs * gamma[f];
    ss[f] = sc;
    ss[128 + f] = beta[f] - mu * sc;
}

// ---------------- graph boundaries (batch is sorted) ----------------
__global__ void k_bounds(const void* batch, const int* __restrict__ flag,
                         int* __restrict__ starts) {
    int g = blockIdx.x * 256 + threadIdx.x;
    if (g > N_GRAPHS) return;
    int f = *flag;
    int lo = 0, hi = N_NODES;
    while (lo < hi) {
        int mid = (lo + hi) >> 1;
        if (geti(batch, mid, f) < g) lo = mid + 1;
        else hi = mid;
    }
    starts[g] = lo;
}

// ---------------- global add pool ----------------
__global__ void k_pool(const float* __restrict__ x, const int* __restrict__ starts,
                       float* __restrict__ gp) {
    int b = blockIdx.x, fi = threadIdx.x;
    int s = starts[b], e = starts[b + 1];
    float acc = 0.f;
    for (int i = s; i < e; ++i) acc += x[(size_t)i * 128 + fi];
    gp[(size_t)b * 128 + fi] = acc;
}

// ---------------- head MLP ----------------
__global__ void k_head(const float* __restrict__ gp, const float* __restrict__ fW1,
                       const float* __restrict__ fb1, const float* __restrict__ fW2,
                       const float* __restrict__ fb2, float* __restrict__ out) {
    __shared__ float gs[128];
    __shared__ float hs[128];
    int b = blockIdx.x, t = threadIdx.x;
    gs[t] = gp[(size_t)b * 128 + t];
    __syncthreads();
    float a = fb1[t];
    for (int k = 0; k < 128; ++k) a += gs[k] * fW1[k * 128 + t];
    hs[t] = fmaxf(a, 0.f);
    __syncthreads();
    if (t < 64) {
        float o = fb2[t];
        for (int k = 0; k < 128; ++k) o += hs[k] * fW2[k * 64 + t];
        out[(size_t)b * 64 + t] = o;
    }
}

extern "C" void kernel_launch(void* const* d_in, const int* in_sizes, int n_in,
                              void* d_out, int out_size, void* d_ws, size_t ws_size,
                              hipStream_t stream) {
    const float* x     = (const float*)d_in[0];
    const void*  ei    = d_in[1];
    const void*  batch = d_in[2];
    const float* W1    = (const float*)d_in[3];
    const float* b1    = (const float*)d_in[4];
    const float* gamma = (const float*)d_in[5];
    const float* beta  = (const float*)d_in[6];
    const float* W2    = (const float*)d_in[7];
    const float* b2    = (const float*)d_in[8];
    const float* fW1   = (const float*)d_in[9];
    const float* fb1   = (const float*)d_in[10];
    const float* fW2   = (const float*)d_in[11];
    const float* fb2   = (const float*)d_in[12];
    float* out = (float*)d_out;

    // workspace layout
    float* bufA = (float*)d_ws;                       // 100000*128 floats
    float* bufB = bufA + (size_t)N_NODES * D;         // 100000*128 floats
    int* deg    = (int*)(bufB + (size_t)N_NODES * D); // 100000
    int* rowp   = deg + N_NODES;                      // 100001
    int* cursor = rowp + N_NODES + 1;                 // 100000
    int* eidx   = cursor + N_NODES;                   // 1600000
    int* starts = eidx + N_EDGES;                     // 1025
    int* dflag  = starts + N_GRAPHS + 1;              // 1
    float* stats = (float*)(dflag + 1);               // 3*256
    float* ssbuf = stats + NL * 256;                  // 3*256
    float* gp    = ssbuf + NL * 256;                  // 1024*128

    hipMemsetAsync(deg, 0, N_NODES * sizeof(int), stream);
    hipMemsetAsync(stats, 0, NL * 256 * sizeof(float), stream);

    k_detect<<<1, 1, 0, stream>>>(ei, dflag);
    k_hist<<<(N_EDGES + 255) / 256, 256, 0, stream>>>(ei, dflag, deg);
    k_scan<<<1, 1024, 0, stream>>>(deg, rowp, cursor);
    k_scatter<<<(N_EDGES + 255) / 256, 256, 0, stream>>>(ei, dflag, cursor, eidx);

    const float* xin = x;
    for (int l = 0; l < NL; ++l) {
        k_agg<<<N_NODES / 4, 256, 0, stream>>>(xin, rowp, eidx, bufB);
        k_lin<1><<<(N_NODES + 255) / 256, 256, 0, stream>>>(
            bufB, W1 + (size_t)l * D * D, b1 + (size_t)l * D, nullptr, bufB,
            stats + (size_t)l * 256);
        k_bnfin<<<1, 128, 0, stream>>>(stats + (size_t)l * 256, gamma + (size_t)l * D,
                                       beta + (size_t)l * D, ssbuf + (size_t)l * 256);
        k_lin<2><<<(N_NODES + 255) / 256, 256, 0, stream>>>(
            bufB, W2 + (size_t)l * D * D, b2 + (size_t)l * D, ssbuf + (size_t)l * 256,
            bufA, nullptr);
        xin = bufA;
    }

    k_bounds<<<5, 256, 0, stream>>>(batch, dflag, starts);
    k_pool<<<N_GRAPHS, 128, 0, stream>>>(bufA, starts, gp);
    k_head<<<N_GRAPHS, 128, 0, stream>>>(gp, fW1, fb1, fW2, fb2, out);
}

// Round 2
// 955.387 us; speedup vs baseline: 1.4195x; 1.4195x over previous
//
#include <hip/hip_runtime.h>

#define N_NODES 100000
#define N_EDGES 1600000
#define N_GRAPHS 1024
#define D 128
#define NL 3
#define BN_EPS 1e-5f

typedef __attribute__((ext_vector_type(8))) short bf16x8;
typedef __attribute__((ext_vector_type(4))) float f32x4;

__device__ __forceinline__ unsigned short f2b(float f) {
    unsigned int u = __float_as_uint(f);
    u += 0x7fff + ((u >> 16) & 1);   // round to nearest even
    return (unsigned short)(u >> 16);
}

// ---------------- dtype-robust index accessor ----------------
// flag==1: indices are int64 (little-endian, values < 2^31) ; flag==0: int32
__device__ __forceinline__ int geti(const void* p, long long i, int f64) {
    return f64 ? (int)((const long long*)p)[i] : ((const int*)p)[i];
}

__global__ void k_detect(const void* ei, int* flag) {
    const int* p = (const int*)ei;
    int acc = 0;
    for (int i = 0; i < 128; ++i) acc |= p[2 * i + 1];
    *flag = (acc == 0) ? 1 : 0;
}

// ---------------- weight prep: Wt[m][n][k] = bf16(W[m][k][n]) ----------------
__global__ void k_wprep(const float* __restrict__ W1, const float* __restrict__ W2,
                        unsigned short* __restrict__ Wt) {
    int m = blockIdx.y;
    int k = blockIdx.x;
    int n = threadIdx.x;
    const float* src = (m < NL) ? (W1 + (size_t)m * D * D) : (W2 + (size_t)(m - NL) * D * D);
    Wt[(size_t)m * D * D + n * D + k] = f2b(src[k * D + n]);
}

// ---------------- CSR build ----------------
__global__ void k_hist(const void* ei, const int* __restrict__ flag, int* __restrict__ deg) {
    int e = blockIdx.x * 256 + threadIdx.x;
    int f = *flag;
    if (e < N_EDGES) {
        int d = geti(ei, (long long)N_EDGES + e, f);
        atomicAdd(&deg[d], 1);
    }
}

// hierarchical exclusive scan over deg[100000]: 98 blocks x 1024 elems
__global__ void k_scan1(const int* __restrict__ deg, int* __restrict__ bsum) {
    __shared__ int wsum[4];
    int tid = threadIdx.x;
    int base = blockIdx.x * 1024 + tid * 4;
    int s = 0;
#pragma unroll
    for (int j = 0; j < 4; ++j) {
        int idx = base + j;
        if (idx < N_NODES) s += deg[idx];
    }
    for (int off = 32; off > 0; off >>= 1) s += __shfl_down(s, off, 64);
    if ((tid & 63) == 0) wsum[tid >> 6] = s;
    __syncthreads();
    if (tid == 0) bsum[blockIdx.x] = wsum[0] + wsum[1] + wsum[2] + wsum[3];
}

__global__ void k_scan2(const int* __restrict__ bsum, int* __restrict__ boff,
                        int* __restrict__ rowp) {
    if (threadIdx.x == 0) {
        int run = 0;
        for (int b = 0; b < 98; ++b) {
            boff[b] = run;
            run += bsum[b];
        }
        rowp[N_NODES] = run;
    }
}

__global__ void k_scan3(const int* __restrict__ deg, const int* __restrict__ boff,
                        int* __restrict__ rowp, int* __restrict__ cursor) {
    __shared__ int wsum[4];
    int tid = threadIdx.x;
    int lane = tid & 63;
    int w = tid >> 6;
    int base = blockIdx.x * 1024 + tid * 4;
    int d[4];
    int tot = 0;
#pragma unroll
    for (int j = 0; j < 4; ++j) {
        int idx = base + j;
        d[j] = (idx < N_NODES) ? deg[idx] : 0;
        tot += d[j];
    }
    int incl = tot;
    for (int off = 1; off < 64; off <<= 1) {
        int v = __shfl_up(incl, off, 64);
        if (lane >= off) incl += v;
    }
    if (lane == 63) wsum[w] = incl;
    __syncthreads();
    int woff = boff[blockIdx.x];
    for (int w2 = 0; w2 < w; ++w2) woff += wsum[w2];
    int ex = woff + incl - tot;
#pragma unroll
    for (int j = 0; j < 4; ++j) {
        int idx = base + j;
        if (idx < N_NODES) {
            rowp[idx] = ex;
            cursor[idx] = ex;
        }
        ex += d[j];
    }
}

__global__ void k_scatter(const void* ei, const int* __restrict__ flag,
                          int* __restrict__ cursor, int* __restrict__ eidx) {
    int e = blockIdx.x * 256 + threadIdx.x;
    int f = *flag;
    if (e < N_EDGES) {
        int s = geti(ei, e, f);
        int d = geti(ei, (long long)N_EDGES + e, f);
        int pos = atomicAdd(&cursor[d], 1);
        eidx[pos] = s;
    }
}

// ---------------- aggregation: out[i] = x[i] + sum_{j in N(i)} x[j] ----------------
__global__ void k_agg(const float* __restrict__ xin, const int* __restrict__ rowp,
                      const int* __restrict__ eidx, float* __restrict__ out) {
    int wid = threadIdx.x >> 6;
    int lane = threadIdx.x & 63;
    int node = blockIdx.x * 4 + wid;
    const float2* x2 = (const float2*)xin;
    float2 acc = x2[(size_t)node * 64 + lane];
    int s = rowp[node], e = rowp[node + 1];
    int i = s;
    for (; i + 1 < e; i += 2) {
        int j0 = eidx[i], j1 = eidx[i + 1];
        float2 v0 = x2[(size_t)j0 * 64 + lane];
        float2 v1 = x2[(size_t)j1 * 64 + lane];
        acc.x += v0.x + v1.x;
        acc.y += v0.y + v1.y;
    }
    if (i < e) {
        int j0 = eidx[i];
        float2 v0 = x2[(size_t)j0 * 64 + lane];
        acc.x += v0.x;
        acc.y += v0.y;
    }
    ((float2*)out)[(size_t)node * 64 + lane] = acc;
}

// ---------------- MFMA GEMM: out[M x 128] = A[M x 128] @ W[128 x 128] + bias ----------
// Wt is pre-transposed bf16 weights: Wt[n][k] = W[k][n].
// MODE 1: plain A load; epilogue stores z and accumulates per-feature sum/sumsq
// MODE 2: A-load applies BN scale/shift + ReLU; epilogue applies ReLU
// Block: 256 threads = 4 waves in 2x2; wave computes 64x64 via 4x4 MFMA 16x16 tiles.
template <int MODE>
__global__ __launch_bounds__(256) void k_lin(const float* __restrict__ A,
                                             const unsigned short* __restrict__ Wt,
                                             const float* __restrict__ bias,
                                             const float* __restrict__ ss,
                                             float* __restrict__ out,
                                             float* __restrict__ stats) {
    __shared__ unsigned short As[128 * 72];    // rows x 64k (pass-local), stride 72
    __shared__ unsigned short Ws[128 * 136];   // n x 128k, stride 136
    __shared__ float ssum[128];
    __shared__ float ssq[128];

    int tid = threadIdx.x;
    int row0 = blockIdx.x * 128;

    if (MODE == 1 && tid < 128) {
        ssum[tid] = 0.f;
        ssq[tid] = 0.f;
    }

    // stage Wt (full K=128) into LDS, row-major [n][k], stride 136
#pragma unroll
    for (int i = 0; i < 8; ++i) {
        int chunk = tid + 256 * i;          // 0..2047
        int n = chunk >> 4;
        int k8 = (chunk & 15) * 8;
        *(bf16x8*)&Ws[n * 136 + k8] = *(const bf16x8*)&Wt[n * 128 + k8];
    }

    auto stageA = [&](int p) {
#pragma unroll
        for (int i = 0; i < 8; ++i) {
            int chunk = tid + 256 * i;      // 0..2047
            int row = chunk >> 4;           // 0..127
            int c4 = (chunk & 15) * 4;      // 0..60
            int gr = row0 + row;
            float4 v = make_float4(0.f, 0.f, 0.f, 0.f);
            if (gr < N_NODES) v = *(const float4*)&A[(size_t)gr * 128 + p * 64 + c4];
            if (MODE == 2) {
                float4 sc = *(const float4*)&ss[p * 64 + c4];
                float4 sh = *(const float4*)&ss[128 + p * 64 + c4];
                v.x = fmaxf(v.x * sc.x + sh.x, 0.f);
                v.y = fmaxf(v.y * sc.y + sh.y, 0.f);
                v.z = fmaxf(v.z * sc.z + sh.z, 0.f);
                v.w = fmaxf(v.w * sc.w + sh.w, 0.f);
            }
            ushort4 b;
            b.x = f2b(v.x); b.y = f2b(v.y); b.z = f2b(v.z); b.w = f2b(v.w);
            *(ushort4*)&As[row * 72 + c4] = b;
        }
    };

    int w = tid >> 6, lane = tid & 63, q = lane >> 4, ln = lane & 15;
    int rbase = (w & 1) * 64, cbase = (w >> 1) * 64;

    f32x4 acc[4][4];
    f32x4 z4 = {0.f, 0.f, 0.f, 0.f};
#pragma unroll
    for (int rt = 0; rt < 4; ++rt)
#pragma unroll
        for (int ct = 0; ct < 4; ++ct) acc[rt][ct] = z4;

    auto mfstep = [&](int p, int ks) {
        bf16x8 af[4], bfr[4];
#pragma unroll
        for (int rt = 0; rt < 4; ++rt)
            af[rt] = *(bf16x8*)&As[(rbase + rt * 16 + ln) * 72 + ks * 32 + q * 8];
#pragma unroll
        for (int ct = 0; ct < 4; ++ct)
            bfr[ct] = *(bf16x8*)&Ws[(cbase + ct * 16 + ln) * 136 + p * 64 + ks * 32 + q * 8];
#pragma unroll
        for (int rt = 0; rt < 4; ++rt)
#pragma unroll
            for (int ct = 0; ct < 4; ++ct)
                acc[rt][ct] = __builtin_amdgcn_mfma_f32_16x16x32_bf16(af[rt], bfr[ct],
                                                                      acc[rt][ct], 0, 0, 0);
    };

    stageA(0);
    __syncthreads();
    mfstep(0, 0);
    mfstep(0, 1);
    __syncthreads();
    stageA(1);
    __syncthreads();
    mfstep(1, 0);
    mfstep(1, 1);

    // epilogue
    float bsv[4], psum[4] = {0.f, 0.f, 0.f, 0.f}, psq[4] = {0.f, 0.f, 0.f, 0.f};
    int col[4];
#pragma unroll
    for (int ct = 0; ct < 4; ++ct) {
        col[ct] = cbase + ct * 16 + ln;
        bsv[ct] = bias[col[ct]];
    }
#pragma unroll
    for (int rt = 0; rt < 4; ++rt) {
        int gr0 = row0 + rbase + rt * 16 + q * 4;
#pragma unroll
        for (int i = 0; i < 4; ++i) {
            int gr = gr0 + i;
            if (gr < N_NODES) {
#pragma unroll
                for (int ct = 0; ct < 4; ++ct) {
                    float z = acc[rt][ct][i] + bsv[ct];
                    if (MODE == 2) z = fmaxf(z, 0.f);
                    out[(size_t)gr * 128 + col[ct]] = z;
                    if (MODE == 1) {
                        psum[ct] += z;
                        psq[ct] += z * z;
                    }
                }
            }
        }
    }

    if (MODE == 1) {
#pragma unroll
        for (int ct = 0; ct < 4; ++ct) {
            atomicAdd(&ssum[col[ct]], psum[ct]);
            atomicAdd(&ssq[col[ct]], psq[ct]);
        }
        __syncthreads();
        if (tid < 128) {
            atomicAdd(&stats[tid], ssum[tid]);
            atomicAdd(&stats[128 + tid], ssq[tid]);
        }
    }
}

// ---------------- BN finalize: scale/shift per feature ----------------
__global__ void k_bnfin(const float* __restrict__ stats, const float* __restrict__ gamma,
                        const float* __restrict__ beta, float* __restrict__ ss) {
    int f = threadIdx.x;
    float s1 = stats[f];
    float s2 = stats[128 + f];
    float mu = s1 / (float)N_NODES;
    float var = s2 / (float)N_NODES - mu * mu;
    float rs = rsqrtf(var + BN_EPS);
    float sc = rs * gamma[f];
    ss[f] = sc;
    ss[128 + f] = beta[f] - mu * sc;
}

// ---------------- graph boundaries (batch is sorted) ----------------
__global__ void k_bounds(const void* batch, const int* __restrict__ flag,
                         int* __restrict__ starts) {
    int g = blockIdx.x * 256 + threadIdx.x;
    if (g > N_GRAPHS) return;
    int f = *flag;
    int lo = 0, hi = N_NODES;
    while (lo < hi) {
        int mid = (lo + hi) >> 1;
        if (geti(batch, mid, f) < g) lo = mid + 1;
        else hi = mid;
    }
    starts[g] = lo;
}

// ---------------- global add pool ----------------
__global__ void k_pool(const float* __restrict__ x, const int* __restrict__ starts,
                       float* __restrict__ gp) {
    int b = blockIdx.x, fi = threadIdx.x;
    int s = starts[b], e = starts[b + 1];
    float acc = 0.f;
    for (int i = s; i < e; ++i) acc += x[(size_t)i * 128 + fi];
    gp[(size_t)b * 128 + fi] = acc;
}

// ---------------- head MLP ----------------
__global__ void k_head(const float* __restrict__ gp, const float* __restrict__ fW1,
                       const float* __restrict__ fb1, const float* __restrict__ fW2,
                       const float* __restrict__ fb2, float* __restrict__ out) {
    __shared__ float gs[128];
    __shared__ float hs[128];
    int b = blockIdx.x, t = threadIdx.x;
    gs[t] = gp[(size_t)b * 128 + t];
    __syncthreads();
    float a = fb1[t];
    for (int k = 0; k < 128; ++k) a += gs[k] * fW1[k * 128 + t];
    hs[t] = fmaxf(a, 0.f);
    __syncthreads();
    if (t < 64) {
        float o = fb2[t];
        for (int k = 0; k < 128; ++k) o += hs[k] * fW2[k * 64 + t];
        out[(size_t)b * 64 + t] = o;
    }
}

extern "C" void kernel_launch(void* const* d_in, const int* in_sizes, int n_in,
                              void* d_out, int out_size, void* d_ws, size_t ws_size,
                              hipStream_t stream) {
    const float* x     = (const float*)d_in[0];
    const void*  ei    = d_in[1];
    const void*  batch = d_in[2];
    const float* W1    = (const float*)d_in[3];
    const float* b1    = (const float*)d_in[4];
    const float* gamma = (const float*)d_in[5];
    const float* beta  = (const float*)d_in[6];
    const float* W2    = (const float*)d_in[7];
    const float* b2    = (const float*)d_in[8];
    const float* fW1   = (const float*)d_in[9];
    const float* fb1   = (const float*)d_in[10];
    const float* fW2   = (const float*)d_in[11];
    const float* fb2   = (const float*)d_in[12];
    float* out = (float*)d_out;

    // workspace layout (all chunks multiple of 16 B)
    float* bufA = (float*)d_ws;                        // 12,800,000 f
    float* bufB = bufA + (size_t)N_NODES * D;          // 12,800,000 f
    int* deg    = (int*)(bufB + (size_t)N_NODES * D);  // 100,000
    int* rowp   = deg + N_NODES;                       // 100,004 (padded)
    int* cursor = rowp + 100004;                       // 100,000
    int* eidx   = cursor + N_NODES;                    // 1,600,000
    int* starts = eidx + N_EDGES;                      // 1,028 (padded)
    int* dflag  = starts + 1028;                       // 4 (padded)
    int* bsum   = dflag + 4;                           // 128
    int* boff   = bsum + 128;                          // 128
    float* stats = (float*)(boff + 128);               // 768
    float* ssbuf = stats + NL * 256;                   // 768
    float* gp    = ssbuf + NL * 256;                   // 131,072
    unsigned short* Wt = (unsigned short*)(gp + (size_t)N_GRAPHS * D);  // 6*16384 ushort

    hipMemsetAsync(deg, 0, N_NODES * sizeof(int), stream);
    hipMemsetAsync(stats, 0, NL * 256 * sizeof(float), stream);

    k_detect<<<1, 1, 0, stream>>>(ei, dflag);
    k_wprep<<<dim3(128, 2 * NL), 128, 0, stream>>>(W1, W2, Wt);
    k_hist<<<(N_EDGES + 255) / 256, 256, 0, stream>>>(ei, dflag, deg);
    k_scan1<<<98, 256, 0, stream>>>(deg, bsum);
    k_scan2<<<1, 64, 0, stream>>>(bsum, boff, rowp);
    k_scan3<<<98, 256, 0, stream>>>(deg, boff, rowp, cursor);
    k_scatter<<<(N_EDGES + 255) / 256, 256, 0, stream>>>(ei, dflag, cursor, eidx);

    const float* xin = x;
    const int gemm_grid = (N_NODES + 127) / 128;  // 782
    for (int l = 0; l < NL; ++l) {
        k_agg<<<N_NODES / 4, 256, 0, stream>>>(xin, rowp, eidx, bufB);
        k_lin<1><<<gemm_grid, 256, 0, stream>>>(
            bufB, Wt + (size_t)l * D * D, b1 + (size_t)l * D, nullptr, bufB,
            stats + (size_t)l * 256);
        k_bnfin<<<1, 128, 0, stream>>>(stats + (size_t)l * 256, gamma + (size_t)l * D,
                                       beta + (size_t)l * D, ssbuf + (size_t)l * 256);
        k_lin<2><<<gemm_grid, 256, 0, stream>>>(
            bufB, Wt + (size_t)(NL + l) * D * D, b2 + (size_t)l * D,
            ssbuf + (size_t)l * 256, bufA, nullptr);
        xin = bufA;
    }

    k_bounds<<<5, 256, 0, stream>>>(batch, dflag, starts);
    k_pool<<<N_GRAPHS, 128, 0, stream>>>(bufA, starts, gp);
    k_head<<<N_GRAPHS, 128, 0, stream>>>(gp, fW1, fb1, fW2, fb2, out);
}

// Round 3
// 875.206 us; speedup vs baseline: 1.5495x; 1.0916x over previous
//
#include <hip/hip_runtime.h>

#define N_NODES 100000
#define N_EDGES 1600000
#define N_GRAPHS 1024
#define D 128
#define NL 3
#define BN_EPS 1e-5f

typedef __attribute__((ext_vector_type(8))) short bf16x8;
typedef __attribute__((ext_vector_type(4))) float f32x4;

__device__ __forceinline__ unsigned short f2b(float f) {
    unsigned int u = __float_as_uint(f);
    u += 0x7fff + ((u >> 16) & 1);   // round to nearest even
    return (unsigned short)(u >> 16);
}

// ---------------- dtype-robust index accessor ----------------
// flag==1: indices are int64 (little-endian, values < 2^31) ; flag==0: int32
__device__ __forceinline__ int geti(const void* p, long long i, int f64) {
    return f64 ? (int)((const long long*)p)[i] : ((const int*)p)[i];
}

__global__ void k_detect(const void* ei, int* flag) {
    int t = threadIdx.x;
    const int* p = (const int*)ei;
    int acc = p[2 * t + 1] | p[2 * (t + 64) + 1];
    unsigned long long b = __ballot(acc != 0);
    if (t == 0) *flag = (b == 0ULL) ? 1 : 0;
}

// ---------------- weight prep: Wt[m][n][k] = bf16(W[m][k][n]) ----------------
__global__ void k_wprep(const float* __restrict__ W1, const float* __restrict__ W2,
                        unsigned short* __restrict__ Wt) {
    int m = blockIdx.y;
    int k = blockIdx.x;
    int n = threadIdx.x;
    const float* src = (m < NL) ? (W1 + (size_t)m * D * D) : (W2 + (size_t)(m - NL) * D * D);
    Wt[(size_t)m * D * D + n * D + k] = f2b(src[k * D + n]);
}

// ---------------- x -> bf16 mirror ----------------
__global__ void k_x2b(const float* __restrict__ x, unsigned short* __restrict__ xb) {
    int i = (blockIdx.x * 256 + threadIdx.x) * 4;
    float4 v = *(const float4*)&x[i];
    ushort4 b;
    b.x = f2b(v.x); b.y = f2b(v.y); b.z = f2b(v.z); b.w = f2b(v.w);
    *(ushort4*)&xb[i] = b;
}

// ---------------- CSR build ----------------
__global__ void k_hist(const void* ei, const int* __restrict__ flag, int* __restrict__ deg) {
    int e = blockIdx.x * 256 + threadIdx.x;
    int f = *flag;
    if (e < N_EDGES) {
        int d = geti(ei, (long long)N_EDGES + e, f);
        atomicAdd(&deg[d], 1);
    }
}

// hierarchical exclusive scan over deg[100000]: 98 blocks x 1024 elems
__global__ void k_scan1(const int* __restrict__ deg, int* __restrict__ bsum) {
    __shared__ int wsum[4];
    int tid = threadIdx.x;
    int base = blockIdx.x * 1024 + tid * 4;
    int s = 0;
#pragma unroll
    for (int j = 0; j < 4; ++j) {
        int idx = base + j;
        if (idx < N_NODES) s += deg[idx];
    }
    for (int off = 32; off > 0; off >>= 1) s += __shfl_down(s, off, 64);
    if ((tid & 63) == 0) wsum[tid >> 6] = s;
    __syncthreads();
    if (tid == 0) bsum[blockIdx.x] = wsum[0] + wsum[1] + wsum[2] + wsum[3];
}

__global__ void k_scan2(const int* __restrict__ bsum, int* __restrict__ boff,
                        int* __restrict__ rowp) {
    if (threadIdx.x == 0) {
        int run = 0;
        for (int b = 0; b < 98; ++b) {
            boff[b] = run;
            run += bsum[b];
        }
        rowp[N_NODES] = run;
    }
}

__global__ void k_scan3(const int* __restrict__ deg, const int* __restrict__ boff,
                        int* __restrict__ rowp, int* __restrict__ cursor) {
    __shared__ int wsum[4];
    int tid = threadIdx.x;
    int lane = tid & 63;
    int w = tid >> 6;
    int base = blockIdx.x * 1024 + tid * 4;
    int d[4];
    int tot = 0;
#pragma unroll
    for (int j = 0; j < 4; ++j) {
        int idx = base + j;
        d[j] = (idx < N_NODES) ? deg[idx] : 0;
        tot += d[j];
    }
    int incl = tot;
    for (int off = 1; off < 64; off <<= 1) {
        int v = __shfl_up(incl, off, 64);
        if (lane >= off) incl += v;
    }
    if (lane == 63) wsum[w] = incl;
    __syncthreads();
    int woff = boff[blockIdx.x];
    for (int w2 = 0; w2 < w; ++w2) woff += wsum[w2];
    int ex = woff + incl - tot;
#pragma unroll
    for (int j = 0; j < 4; ++j) {
        int idx = base + j;
        if (idx < N_NODES) {
            rowp[idx] = ex;
            cursor[idx] = ex;
        }
        ex += d[j];
    }
}

__global__ void k_scatter(const void* ei, const int* __restrict__ flag,
                          int* __restrict__ cursor, int* __restrict__ eidx) {
    int e = blockIdx.x * 256 + threadIdx.x;
    int f = *flag;
    if (e < N_EDGES) {
        int s = geti(ei, e, f);
        int d = geti(ei, (long long)N_EDGES + e, f);
        int pos = atomicAdd(&cursor[d], 1);
        eidx[pos] = s;
    }
}

// ------------- aggregation (bf16 in / bf16 out, fp32 accumulate) -------------
// out[i] = x[i] + sum_{j in N(i)} x[j]; one wave per node, one dword (2 bf16)/lane
__global__ void k_aggb(const unsigned short* __restrict__ xb, const int* __restrict__ rowp,
                       const int* __restrict__ eidx, unsigned short* __restrict__ aggb) {
    int wid = threadIdx.x >> 6;
    int lane = threadIdx.x & 63;
    int node = blockIdx.x * 4 + wid;
    const unsigned int* x1 = (const unsigned int*)xb;   // 64 dwords per row
    unsigned int u = x1[(size_t)node * 64 + lane];
    float accx = __uint_as_float(u << 16);
    float accy = __uint_as_float(u & 0xffff0000u);
    int s = rowp[node], e = rowp[node + 1];
    int i = s;
    for (; i + 1 < e; i += 2) {
        unsigned int v0 = x1[(size_t)eidx[i] * 64 + lane];
        unsigned int v1 = x1[(size_t)eidx[i + 1] * 64 + lane];
        accx += __uint_as_float(v0 << 16) + __uint_as_float(v1 << 16);
        accy += __uint_as_float(v0 & 0xffff0000u) + __uint_as_float(v1 & 0xffff0000u);
    }
    if (i < e) {
        unsigned int v0 = x1[(size_t)eidx[i] * 64 + lane];
        accx += __uint_as_float(v0 << 16);
        accy += __uint_as_float(v0 & 0xffff0000u);
    }
    unsigned int o = ((unsigned int)f2b(accy) << 16) | f2b(accx);
    ((unsigned int*)aggb)[(size_t)node * 64 + lane] = o;
}

// ---------------- MFMA GEMM: out[M x 128] = A[M x 128] @ W[128 x 128] + bias ----------
// Wt is pre-transposed bf16 weights: Wt[n][k] = W[k][n].
// MODE 1: A is bf16 (aggb); epilogue stores z fp32 and accumulates per-feature sum/sumsq
// MODE 2: A is fp32; A-load applies BN scale/shift + ReLU; epilogue ReLU,
//         writes fp32 (if outf) and/or bf16 mirror (if outb). outf may alias A (in-place).
template <int MODE>
__global__ __launch_bounds__(256) void k_lin(const void* __restrict__ Ap,
                                             const unsigned short* __restrict__ Wt,
                                             const float* __restrict__ bias,
                                             const float* __restrict__ ss,
                                             float* __restrict__ outf,
                                             unsigned short* __restrict__ outb,
                                             float* __restrict__ stats) {
    __shared__ unsigned short As[128 * 136];   // rows x 128k, stride 136 (2-way max)
    __shared__ unsigned short Ws[128 * 136];   // n x 128k, stride 136
    __shared__ float ssum[128];
    __shared__ float ssq[128];

    int tid = threadIdx.x;
    int row0 = blockIdx.x * 128;

    if (MODE == 1 && tid < 128) {
        ssum[tid] = 0.f;
        ssq[tid] = 0.f;
    }

    // stage Wt (full K=128) into LDS
#pragma unroll
    for (int i = 0; i < 8; ++i) {
        int chunk = tid + 256 * i;          // 0..2047
        int n = chunk >> 4;
        int k8 = (chunk & 15) * 8;
        *(bf16x8*)&Ws[n * 136 + k8] = *(const bf16x8*)&Wt[n * 128 + k8];
    }

    // stage A (full K=128) into LDS
    if (MODE == 1) {
        const unsigned short* A = (const unsigned short*)Ap;
#pragma unroll
        for (int i = 0; i < 8; ++i) {
            int chunk = tid + 256 * i;
            int row = chunk >> 4;
            int k8 = (chunk & 15) * 8;
            int gr = row0 + row;
            bf16x8 v = {0, 0, 0, 0, 0, 0, 0, 0};
            if (gr < N_NODES) v = *(const bf16x8*)&A[(size_t)gr * 128 + k8];
            *(bf16x8*)&As[row * 136 + k8] = v;
        }
    } else {
        const float* A = (const float*)Ap;
#pragma unroll
        for (int i = 0; i < 8; ++i) {
            int chunk = tid + 256 * i;
            int row = chunk >> 4;
            int c8 = (chunk & 15) * 8;
            int gr = row0 + row;
            float4 v0 = make_float4(0.f, 0.f, 0.f, 0.f), v1 = v0;
            if (gr < N_NODES) {
                v0 = *(const float4*)&A[(size_t)gr * 128 + c8];
                v1 = *(const float4*)&A[(size_t)gr * 128 + c8 + 4];
            }
            float4 sc0 = *(const float4*)&ss[c8];
            float4 sc1 = *(const float4*)&ss[c8 + 4];
            float4 sh0 = *(const float4*)&ss[128 + c8];
            float4 sh1 = *(const float4*)&ss[128 + c8 + 4];
            ushort4 b0, b1;
            b0.x = f2b(fmaxf(v0.x * sc0.x + sh0.x, 0.f));
            b0.y = f2b(fmaxf(v0.y * sc0.y + sh0.y, 0.f));
            b0.z = f2b(fmaxf(v0.z * sc0.z + sh0.z, 0.f));
            b0.w = f2b(fmaxf(v0.w * sc0.w + sh0.w, 0.f));
            b1.x = f2b(fmaxf(v1.x * sc1.x + sh1.x, 0.f));
            b1.y = f2b(fmaxf(v1.y * sc1.y + sh1.y, 0.f));
            b1.z = f2b(fmaxf(v1.z * sc1.z + sh1.z, 0.f));
            b1.w = f2b(fmaxf(v1.w * sc1.w + sh1.w, 0.f));
            *(ushort4*)&As[row * 136 + c8] = b0;
            *(ushort4*)&As[row * 136 + c8 + 4] = b1;
        }
    }
    __syncthreads();

    int w = tid >> 6, lane = tid & 63, q = lane >> 4, ln = lane & 15;
    int rbase = (w & 1) * 64, cbase = (w >> 1) * 64;

    f32x4 acc[4][4];
    f32x4 z4 = {0.f, 0.f, 0.f, 0.f};
#pragma unroll
    for (int rt = 0; rt < 4; ++rt)
#pragma unroll
        for (int ct = 0; ct < 4; ++ct) acc[rt][ct] = z4;

#pragma unroll
    for (int ks = 0; ks < 4; ++ks) {
        bf16x8 af[4], bfr[4];
#pragma unroll
        for (int rt = 0; rt < 4; ++rt)
            af[rt] = *(bf16x8*)&As[(rbase + rt * 16 + ln) * 136 + ks * 32 + q * 8];
#pragma unroll
        for (int ct = 0; ct < 4; ++ct)
            bfr[ct] = *(bf16x8*)&Ws[(cbase + ct * 16 + ln) * 136 + ks * 32 + q * 8];
#pragma unroll
        for (int rt = 0; rt < 4; ++rt)
#pragma unroll
            for (int ct = 0; ct < 4; ++ct)
                acc[rt][ct] = __builtin_amdgcn_mfma_f32_16x16x32_bf16(af[rt], bfr[ct],
                                                                      acc[rt][ct], 0, 0, 0);
    }

    // epilogue
    float bsv[4], psum[4] = {0.f, 0.f, 0.f, 0.f}, psq[4] = {0.f, 0.f, 0.f, 0.f};
    int col[4];
#pragma unroll
    for (int ct = 0; ct < 4; ++ct) {
        col[ct] = cbase + ct * 16 + ln;
        bsv[ct] = bias[col[ct]];
    }
#pragma unroll
    for (int rt = 0; rt < 4; ++rt) {
        int gr0 = row0 + rbase + rt * 16 + q * 4;
#pragma unroll
        for (int i = 0; i < 4; ++i) {
            int gr = gr0 + i;
            if (gr < N_NODES) {
#pragma unroll
                for (int ct = 0; ct < 4; ++ct) {
                    float z = acc[rt][ct][i] + bsv[ct];
                    if (MODE == 2) {
                        z = fmaxf(z, 0.f);
                        if (outf) outf[(size_t)gr * 128 + col[ct]] = z;
                        if (outb) outb[(size_t)gr * 128 + col[ct]] = f2b(z);
                    } else {
                        outf[(size_t)gr * 128 + col[ct]] = z;
                        psum[ct] += z;
                        psq[ct] += z * z;
                    }
                }
            }
        }
    }

    if (MODE == 1) {
#pragma unroll
        for (int ct = 0; ct < 4; ++ct) {
            atomicAdd(&ssum[col[ct]], psum[ct]);
            atomicAdd(&ssq[col[ct]], psq[ct]);
        }
        __syncthreads();
        if (tid < 128) {
            atomicAdd(&stats[tid], ssum[tid]);
            atomicAdd(&stats[128 + tid], ssq[tid]);
        }
    }
}

// ---------------- BN finalize: scale/shift per feature ----------------
__global__ void k_bnfin(const float* __restrict__ stats, const float* __restrict__ gamma,
                        const float* __restrict__ beta, float* __restrict__ ss) {
    int f = threadIdx.x;
    float s1 = stats[f];
    float s2 = stats[128 + f];
    float mu = s1 / (float)N_NODES;
    float var = s2 / (float)N_NODES - mu * mu;
    float rs = rsqrtf(var + BN_EPS);
    float sc = rs * gamma[f];
    ss[f] = sc;
    ss[128 + f] = beta[f] - mu * sc;
}

// ---------------- graph boundaries (batch is sorted) ----------------
__global__ void k_bounds(const void* batch, const int* __restrict__ flag,
                         int* __restrict__ starts) {
    int g = blockIdx.x * 256 + threadIdx.x;
    if (g > N_GRAPHS) return;
    int f = *flag;
    int lo = 0, hi = N_NODES;
    while (lo < hi) {
        int mid = (lo + hi) >> 1;
        if (geti(batch, mid, f) < g) lo = mid + 1;
        else hi = mid;
    }
    starts[g] = lo;
}

// ---------------- global add pool ----------------
__global__ void k_pool(const float* __restrict__ x, const int* __restrict__ starts,
                       float* __restrict__ gp) {
    int b = blockIdx.x, fi = threadIdx.x;
    int s = starts[b], e = starts[b + 1];
    float acc = 0.f;
    for (int i = s; i < e; ++i) acc += x[(size_t)i * 128 + fi];
    gp[(size_t)b * 128 + fi] = acc;
}

// ---------------- head MLP ----------------
__global__ void k_head(const float* __restrict__ gp, const float* __restrict__ fW1,
                       const float* __restrict__ fb1, const float* __restrict__ fW2,
                       const float* __restrict__ fb2, float* __restrict__ out) {
    __shared__ float gs[128];
    __shared__ float hs[128];
    int b = blockIdx.x, t = threadIdx.x;
    gs[t] = gp[(size_t)b * 128 + t];
    __syncthreads();
    float a = fb1[t];
    for (int k = 0; k < 128; ++k) a += gs[k] * fW1[k * 128 + t];
    hs[t] = fmaxf(a, 0.f);
    __syncthreads();
    if (t < 64) {
        float o = fb2[t];
        for (int k = 0; k < 128; ++k) o += hs[k] * fW2[k * 64 + t];
        out[(size_t)b * 64 + t] = o;
    }
}

extern "C" void kernel_launch(void* const* d_in, const int* in_sizes, int n_in,
                              void* d_out, int out_size, void* d_ws, size_t ws_size,
                              hipStream_t stream) {
    const float* x     = (const float*)d_in[0];
    const void*  ei    = d_in[1];
    const void*  batch = d_in[2];
    const float* W1    = (const float*)d_in[3];
    const float* b1    = (const float*)d_in[4];
    const float* gamma = (const float*)d_in[5];
    const float* beta  = (const float*)d_in[6];
    const float* W2    = (const float*)d_in[7];
    const float* b2    = (const float*)d_in[8];
    const float* fW1   = (const float*)d_in[9];
    const float* fb1   = (const float*)d_in[10];
    const float* fW2   = (const float*)d_in[11];
    const float* fb2   = (const float*)d_in[12];
    float* out = (float*)d_out;

    // workspace layout (all chunks multiple of 16 B)
    float* bufB = (float*)d_ws;                                    // 12.8M f (z / final x)
    unsigned short* xb   = (unsigned short*)(bufB + (size_t)N_NODES * D);  // 12.8M us
    unsigned short* aggb = xb + (size_t)N_NODES * D;               // 12.8M us
    int* deg    = (int*)(aggb + (size_t)N_NODES * D);              // 100,000
    int* rowp   = deg + N_NODES;                                   // 100,004 (padded)
    int* cursor = rowp + 100004;                                   // 100,000
    int* eidx   = cursor + N_NODES;                                // 1,600,000
    int* starts = eidx + N_EDGES;                                  // 1,028 (padded)
    int* dflag  = starts + 1028;                                   // 4 (padded)
    int* bsum   = dflag + 4;                                       // 128
    int* boff   = bsum + 128;                                      // 128
    float* stats = (float*)(boff + 128);                           // 768
    float* ssbuf = stats + NL * 256;                               // 768
    float* gp    = ssbuf + NL * 256;                               // 131,072
    unsigned short* Wt = (unsigned short*)(gp + (size_t)N_GRAPHS * D);  // 6*16384 ushort

    hipMemsetAsync(deg, 0, N_NODES * sizeof(int), stream);
    hipMemsetAsync(stats, 0, NL * 256 * sizeof(float), stream);

    k_detect<<<1, 64, 0, stream>>>(ei, dflag);
    k_wprep<<<dim3(128, 2 * NL), 128, 0, stream>>>(W1, W2, Wt);
    k_x2b<<<(N_NODES * D) / 1024, 256, 0, stream>>>(x, xb);
    k_hist<<<(N_EDGES + 255) / 256, 256, 0, stream>>>(ei, dflag, deg);
    k_scan1<<<98, 256, 0, stream>>>(deg, bsum);
    k_scan2<<<1, 64, 0, stream>>>(bsum, boff, rowp);
    k_scan3<<<98, 256, 0, stream>>>(deg, boff, rowp, cursor);
    k_scatter<<<(N_EDGES + 255) / 256, 256, 0, stream>>>(ei, dflag, cursor, eidx);

    const int gemm_grid = (N_NODES + 127) / 128;  // 782
    for (int l = 0; l < NL; ++l) {
        bool last = (l == NL - 1);
        k_aggb<<<N_NODES / 4, 256, 0, stream>>>(xb, rowp, eidx, aggb);
        k_lin<1><<<gemm_grid, 256, 0, stream>>>(
            aggb, Wt + (size_t)l * D * D, b1 + (size_t)l * D, nullptr, bufB, nullptr,
            stats + (size_t)l * 256);
        k_bnfin<<<1, 128, 0, stream>>>(stats + (size_t)l * 256, gamma + (size_t)l * D,
                                       beta + (size_t)l * D, ssbuf + (size_t)l * 256);
        k_lin<2><<<gemm_grid, 256, 0, stream>>>(
            bufB, Wt + (size_t)(NL + l) * D * D, b2 + (size_t)l * D,
            ssbuf + (size_t)l * 256, last ? bufB : nullptr, last ? nullptr : xb, nullptr);
    }

    k_bounds<<<5, 256, 0, stream>>>(batch, dflag, starts);
    k_pool<<<N_GRAPHS, 128, 0, stream>>>(bufB, starts, gp);
    k_head<<<N_GRAPHS, 128, 0, stream>>>(gp, fW1, fb1, fW2, fb2, out);
}

// Round 4
// 714.600 us; speedup vs baseline: 1.8978x; 1.2247x over previous
//
#include <hip/hip_runtime.h>

#define N_NODES 100000
#define N_EDGES 1600000
#define N_GRAPHS 1024
#define D 128
#define NL 3
#define BN_EPS 1e-5f
#define SCAT_P 8
#define SLICE ((N_NODES + SCAT_P - 1) / SCAT_P)   // 12500

typedef __attribute__((ext_vector_type(8))) short bf16x8;
typedef __attribute__((ext_vector_type(4))) float f32x4;

__device__ __forceinline__ unsigned short f2b(float f) {
    unsigned int u = __float_as_uint(f);
    u += 0x7fff + ((u >> 16) & 1);   // round to nearest even
    return (unsigned short)(u >> 16);
}
__device__ __forceinline__ float b2f(unsigned short b) {
    return __uint_as_float(((unsigned int)b) << 16);
}

// ---------------- dtype-robust index accessor ----------------
__device__ __forceinline__ int geti(const void* p, long long i, int f64) {
    return f64 ? (int)((const long long*)p)[i] : ((const int*)p)[i];
}

__global__ void k_detect(const void* ei, int* flag) {
    int t = threadIdx.x;
    const int* p = (const int*)ei;
    int acc = p[2 * t + 1] | p[2 * (t + 64) + 1];
    unsigned long long b = __ballot(acc != 0);
    if (t == 0) *flag = (b == 0ULL) ? 1 : 0;
}

// ---------------- weight prep: Wt[m][n][k] = bf16(W[m][k][n]) ----------------
__global__ void k_wprep(const float* __restrict__ W1, const float* __restrict__ W2,
                        unsigned short* __restrict__ Wt) {
    int m = blockIdx.y;
    int k = blockIdx.x;
    int n = threadIdx.x;
    const float* src = (m < NL) ? (W1 + (size_t)m * D * D) : (W2 + (size_t)(m - NL) * D * D);
    Wt[(size_t)m * D * D + n * D + k] = f2b(src[k * D + n]);
}

// ---------------- x -> bf16 mirror ----------------
__global__ void k_x2b(const float* __restrict__ x, unsigned short* __restrict__ xb) {
    int i = (blockIdx.x * 256 + threadIdx.x) * 4;
    float4 v = *(const float4*)&x[i];
    ushort4 b;
    b.x = f2b(v.x); b.y = f2b(v.y); b.z = f2b(v.z); b.w = f2b(v.w);
    *(ushort4*)&xb[i] = b;
}

// ---------------- CSR build ----------------
__global__ void k_hist(const void* ei, const int* __restrict__ flag, int* __restrict__ deg) {
    int e = blockIdx.x * 256 + threadIdx.x;
    int f = *flag;
    if (e < N_EDGES) {
        int d = geti(ei, (long long)N_EDGES + e, f);
        atomicAdd(&deg[d], 1);
    }
}

__global__ void k_scan1(const int* __restrict__ deg, int* __restrict__ bsum) {
    __shared__ int wsum[4];
    int tid = threadIdx.x;
    int base = blockIdx.x * 1024 + tid * 4;
    int s = 0;
#pragma unroll
    for (int j = 0; j < 4; ++j) {
        int idx = base + j;
        if (idx < N_NODES) s += deg[idx];
    }
    for (int off = 32; off > 0; off >>= 1) s += __shfl_down(s, off, 64);
    if ((tid & 63) == 0) wsum[tid >> 6] = s;
    __syncthreads();
    if (tid == 0) bsum[blockIdx.x] = wsum[0] + wsum[1] + wsum[2] + wsum[3];
}

__global__ void k_scan2(const int* __restrict__ bsum, int* __restrict__ boff,
                        int* __restrict__ rowp) {
    if (threadIdx.x == 0) {
        int run = 0;
        for (int b = 0; b < 98; ++b) {
            boff[b] = run;
            run += bsum[b];
        }
        rowp[N_NODES] = run;
    }
}

__global__ void k_scan3(const int* __restrict__ deg, const int* __restrict__ boff,
                        int* __restrict__ rowp, int* __restrict__ cursor) {
    __shared__ int wsum[4];
    int tid = threadIdx.x;
    int lane = tid & 63;
    int w = tid >> 6;
    int base = blockIdx.x * 1024 + tid * 4;
    int d[4];
    int tot = 0;
#pragma unroll
    for (int j = 0; j < 4; ++j) {
        int idx = base + j;
        d[j] = (idx < N_NODES) ? deg[idx] : 0;
        tot += d[j];
    }
    int incl = tot;
    for (int off = 1; off < 64; off <<= 1) {
        int v = __shfl_up(incl, off, 64);
        if (lane >= off) incl += v;
    }
    if (lane == 63) wsum[w] = incl;
    __syncthreads();
    int woff = boff[blockIdx.x];
    for (int w2 = 0; w2 < w; ++w2) woff += wsum[w2];
    int ex = woff + incl - tot;
#pragma unroll
    for (int j = 0; j < 4; ++j) {
        int idx = base + j;
        if (idx < N_NODES) {
            rowp[idx] = ex;
            cursor[idx] = ex;
        }
        ex += d[j];
    }
}

// Sliced scatter: block handles dst-slice p = blockIdx.x & 7 (XCD round-robin),
// edge chunk blockIdx.x >> 3 (1024 edges). All writes to slice p come from one
// XCD -> eidx lines merge in that XCD's L2 (write amplification ~1x).
__global__ void k_scatter(const void* ei, const int* __restrict__ flag,
                          int* __restrict__ cursor, int* __restrict__ eidx) {
    int p = blockIdx.x & (SCAT_P - 1);
    int chunk = blockIdx.x >> 3;
    long long base = (long long)chunk * 1024 + threadIdx.x * 4;
    int f = *flag;
    int lo = p * SLICE;
    int hi = lo + SLICE;
#pragma unroll
    for (int j = 0; j < 4; ++j) {
        long long e = base + j;
        if (e < N_EDGES) {
            int d = geti(ei, (long long)N_EDGES + e, f);
            if (d >= lo && d < hi) {
                int s = geti(ei, e, f);
                int pos = atomicAdd(&cursor[d], 1);
                eidx[pos] = s;
            }
        }
    }
}

// ------------- aggregation (bf16 in / bf16 out, fp32 accumulate) -------------
__global__ void k_aggb(const unsigned short* __restrict__ xb, const int* __restrict__ rowp,
                       const int* __restrict__ eidx, unsigned short* __restrict__ aggb) {
    int wid = threadIdx.x >> 6;
    int lane = threadIdx.x & 63;
    int node = blockIdx.x * 4 + wid;
    const unsigned int* x1 = (const unsigned int*)xb;   // 64 dwords per row
    unsigned int u = x1[(size_t)node * 64 + lane];
    float accx = __uint_as_float(u << 16);
    float accy = __uint_as_float(u & 0xffff0000u);
    int s = rowp[node], e = rowp[node + 1];
    int i = s;
    for (; i + 3 < e; i += 4) {
        unsigned int v0 = x1[(size_t)eidx[i] * 64 + lane];
        unsigned int v1 = x1[(size_t)eidx[i + 1] * 64 + lane];
        unsigned int v2 = x1[(size_t)eidx[i + 2] * 64 + lane];
        unsigned int v3 = x1[(size_t)eidx[i + 3] * 64 + lane];
        accx += __uint_as_float(v0 << 16) + __uint_as_float(v1 << 16);
        accy += __uint_as_float(v0 & 0xffff0000u) + __uint_as_float(v1 & 0xffff0000u);
        accx += __uint_as_float(v2 << 16) + __uint_as_float(v3 << 16);
        accy += __uint_as_float(v2 & 0xffff0000u) + __uint_as_float(v3 & 0xffff0000u);
    }
    for (; i < e; ++i) {
        unsigned int v0 = x1[(size_t)eidx[i] * 64 + lane];
        accx += __uint_as_float(v0 << 16);
        accy += __uint_as_float(v0 & 0xffff0000u);
    }
    unsigned int o = ((unsigned int)f2b(accy) << 16) | f2b(accx);
    ((unsigned int*)aggb)[(size_t)node * 64 + lane] = o;
}

// ---------------- MFMA GEMM: out = A @ W + bias (A, out bf16) ----------------
// MODE 1: A = agg (bf16); epilogue stores z bf16 + accumulates per-feature sum/sumsq
// MODE 2: A = z (bf16); A-load applies BN (scale/shift computed in-block from
//         stats/gamma/beta) + ReLU; epilogue ReLU, stores bf16.
template <int MODE>
__global__ __launch_bounds__(256) void k_lin(const unsigned short* __restrict__ A,
                                             const unsigned short* __restrict__ Wt,
                                             const float* __restrict__ bias,
                                             float* __restrict__ stats,
                                             const float* __restrict__ gamma,
                                             const float* __restrict__ beta,
                                             unsigned short* __restrict__ outb) {
    __shared__ unsigned short As[128 * 136];   // rows x 128k, stride 136
    __shared__ unsigned short Ws[128 * 136];   // n x 128k, stride 136
    __shared__ float red1[128];
    __shared__ float red2[128];

    int tid = threadIdx.x;
    int row0 = blockIdx.x * 128;

    if (MODE == 1 && tid < 128) {
        red1[tid] = 0.f;
        red2[tid] = 0.f;
    }
    if (MODE == 2 && tid < 128) {
        // recompute BN scale/shift from global stats (fused k_bnfin)
        float s1 = stats[tid];
        float s2 = stats[128 + tid];
        float mu = s1 / (float)N_NODES;
        float var = s2 / (float)N_NODES - mu * mu;
        float sc = rsqrtf(var + BN_EPS) * gamma[tid];
        red1[tid] = sc;               // scale
        red2[tid] = beta[tid] - mu * sc;  // shift
    }

    // stage Wt (full K=128) into LDS
#pragma unroll
    for (int i = 0; i < 8; ++i) {
        int chunk = tid + 256 * i;          // 0..2047
        int n = chunk >> 4;
        int k8 = (chunk & 15) * 8;
        *(bf16x8*)&Ws[n * 136 + k8] = *(const bf16x8*)&Wt[n * 128 + k8];
    }

    if (MODE == 2) __syncthreads();  // red1/red2 ready before A-stage uses them

    // stage A (full K=128) into LDS
#pragma unroll
    for (int i = 0; i < 8; ++i) {
        int chunk = tid + 256 * i;
        int row = chunk >> 4;
        int k8 = (chunk & 15) * 8;
        int gr = row0 + row;
        bf16x8 v = {0, 0, 0, 0, 0, 0, 0, 0};
        if (gr < N_NODES) v = *(const bf16x8*)&A[(size_t)gr * 128 + k8];
        if (MODE == 2) {
            bf16x8 o;
#pragma unroll
            for (int t = 0; t < 8; ++t) {
                float xv = b2f((unsigned short)v[t]);
                float z = fmaxf(xv * red1[k8 + t] + red2[k8 + t], 0.f);
                o[t] = (short)f2b(z);
            }
            v = o;
        }
        *(bf16x8*)&As[row * 136 + k8] = v;
    }
    __syncthreads();

    int w = tid >> 6, lane = tid & 63, q = lane >> 4, ln = lane & 15;
    int rbase = (w & 1) * 64, cbase = (w >> 1) * 64;

    f32x4 acc[4][4];
    f32x4 z4 = {0.f, 0.f, 0.f, 0.f};
#pragma unroll
    for (int rt = 0; rt < 4; ++rt)
#pragma unroll
        for (int ct = 0; ct < 4; ++ct) acc[rt][ct] = z4;

#pragma unroll
    for (int ks = 0; ks < 4; ++ks) {
        bf16x8 af[4], bfr[4];
#pragma unroll
        for (int rt = 0; rt < 4; ++rt)
            af[rt] = *(bf16x8*)&As[(rbase + rt * 16 + ln) * 136 + ks * 32 + q * 8];
#pragma unroll
        for (int ct = 0; ct < 4; ++ct)
            bfr[ct] = *(bf16x8*)&Ws[(cbase + ct * 16 + ln) * 136 + ks * 32 + q * 8];
#pragma unroll
        for (int rt = 0; rt < 4; ++rt)
#pragma unroll
            for (int ct = 0; ct < 4; ++ct)
                acc[rt][ct] = __builtin_amdgcn_mfma_f32_16x16x32_bf16(af[rt], bfr[ct],
                                                                      acc[rt][ct], 0, 0, 0);
    }

    if (MODE == 1) __syncthreads();  // re-init red1/red2 for stats reduction
    if (MODE == 1 && tid < 128) {
        red1[tid] = 0.f;
        red2[tid] = 0.f;
    }
    if (MODE == 1) __syncthreads();

    // epilogue
    float bsv[4], psum[4] = {0.f, 0.f, 0.f, 0.f}, psq[4] = {0.f, 0.f, 0.f, 0.f};
    int col[4];
#pragma unroll
    for (int ct = 0; ct < 4; ++ct) {
        col[ct] = cbase + ct * 16 + ln;
        bsv[ct] = bias[col[ct]];
    }
#pragma unroll
    for (int rt = 0; rt < 4; ++rt) {
        int gr0 = row0 + rbase + rt * 16 + q * 4;
#pragma unroll
        for (int i = 0; i < 4; ++i) {
            int gr = gr0 + i;
            if (gr < N_NODES) {
#pragma unroll
                for (int ct = 0; ct < 4; ++ct) {
                    float z = acc[rt][ct][i] + bsv[ct];
                    if (MODE == 2) {
                        z = fmaxf(z, 0.f);
                        outb[(size_t)gr * 128 + col[ct]] = f2b(z);
                    } else {
                        outb[(size_t)gr * 128 + col[ct]] = f2b(z);
                        psum[ct] += z;
                        psq[ct] += z * z;
                    }
                }
            }
        }
    }

    if (MODE == 1) {
#pragma unroll
        for (int ct = 0; ct < 4; ++ct) {
            atomicAdd(&red1[col[ct]], psum[ct]);
            atomicAdd(&red2[col[ct]], psq[ct]);
        }
        __syncthreads();
        if (tid < 128) {
            atomicAdd(&stats[tid], red1[tid]);
            atomicAdd(&stats[128 + tid], red2[tid]);
        }
    }
}

// ---------------- graph boundaries (batch is sorted) ----------------
__global__ void k_bounds(const void* batch, const int* __restrict__ flag,
                         int* __restrict__ starts) {
    int g = blockIdx.x * 256 + threadIdx.x;
    if (g > N_GRAPHS) return;
    int f = *flag;
    int lo = 0, hi = N_NODES;
    while (lo < hi) {
        int mid = (lo + hi) >> 1;
        if (geti(batch, mid, f) < g) lo = mid + 1;
        else hi = mid;
    }
    starts[g] = lo;
}

// ---------------- global add pool (bf16 in, fp32 out) ----------------
__global__ void k_pool(const unsigned short* __restrict__ xb, const int* __restrict__ starts,
                       float* __restrict__ gp) {
    int b = blockIdx.x, fi = threadIdx.x;
    int s = starts[b], e = starts[b + 1];
    float acc = 0.f;
    for (int i = s; i < e; ++i) acc += b2f(xb[(size_t)i * 128 + fi]);
    gp[(size_t)b * 128 + fi] = acc;
}

// ---------------- head MLP ----------------
__global__ void k_head(const float* __restrict__ gp, const float* __restrict__ fW1,
                       const float* __restrict__ fb1, const float* __restrict__ fW2,
                       const float* __restrict__ fb2, float* __restrict__ out) {
    __shared__ float gs[128];
    __shared__ float hs[128];
    int b = blockIdx.x, t = threadIdx.x;
    gs[t] = gp[(size_t)b * 128 + t];
    __syncthreads();
    float a = fb1[t];
    for (int k = 0; k < 128; ++k) a += gs[k] * fW1[k * 128 + t];
    hs[t] = fmaxf(a, 0.f);
    __syncthreads();
    if (t < 64) {
        float o = fb2[t];
        for (int k = 0; k < 128; ++k) o += hs[k] * fW2[k * 64 + t];
        out[(size_t)b * 64 + t] = o;
    }
}

extern "C" void kernel_launch(void* const* d_in, const int* in_sizes, int n_in,
                              void* d_out, int out_size, void* d_ws, size_t ws_size,
                              hipStream_t stream) {
    const float* x     = (const float*)d_in[0];
    const void*  ei    = d_in[1];
    const void*  batch = d_in[2];
    const float* W1    = (const float*)d_in[3];
    const float* b1    = (const float*)d_in[4];
    const float* gamma = (const float*)d_in[5];
    const float* beta  = (const float*)d_in[6];
    const float* W2    = (const float*)d_in[7];
    const float* b2    = (const float*)d_in[8];
    const float* fW1   = (const float*)d_in[9];
    const float* fb1   = (const float*)d_in[10];
    const float* fW2   = (const float*)d_in[11];
    const float* fb2   = (const float*)d_in[12];
    float* out = (float*)d_out;

    // workspace layout (all chunks multiple of 16 B)
    unsigned short* xb   = (unsigned short*)d_ws;                  // 12.8M us
    unsigned short* zb   = xb + (size_t)N_NODES * D;               // 12.8M us
    unsigned short* aggb = zb + (size_t)N_NODES * D;               // 12.8M us
    int* deg    = (int*)(aggb + (size_t)N_NODES * D);              // 100,000
    int* rowp   = deg + N_NODES;                                   // 100,004 (padded)
    int* cursor = rowp + 100004;                                   // 100,000
    int* eidx   = cursor + N_NODES;                                // 1,600,000
    int* starts = eidx + N_EDGES;                                  // 1,028 (padded)
    int* dflag  = starts + 1028;                                   // 4 (padded)
    int* bsum   = dflag + 4;                                       // 128
    int* boff   = bsum + 128;                                      // 128
    float* stats = (float*)(boff + 128);                           // 768
    float* gp    = stats + NL * 256;                               // 131,072
    unsigned short* Wt = (unsigned short*)(gp + (size_t)N_GRAPHS * D);  // 6*16384 us

    hipMemsetAsync(deg, 0, N_NODES * sizeof(int), stream);
    hipMemsetAsync(stats, 0, NL * 256 * sizeof(float), stream);

    k_detect<<<1, 64, 0, stream>>>(ei, dflag);
    k_wprep<<<dim3(128, 2 * NL), 128, 0, stream>>>(W1, W2, Wt);
    k_x2b<<<(N_NODES * D) / 1024, 256, 0, stream>>>(x, xb);
    k_hist<<<(N_EDGES + 255) / 256, 256, 0, stream>>>(ei, dflag, deg);
    k_scan1<<<98, 256, 0, stream>>>(deg, bsum);
    k_scan2<<<1, 64, 0, stream>>>(bsum, boff, rowp);
    k_scan3<<<98, 256, 0, stream>>>(deg, boff, rowp, cursor);
    k_scatter<<<SCAT_P * ((N_EDGES + 1023) / 1024), 256, 0, stream>>>(ei, dflag, cursor, eidx);

    const int gemm_grid = (N_NODES + 127) / 128;  // 782
    for (int l = 0; l < NL; ++l) {
        k_aggb<<<N_NODES / 4, 256, 0, stream>>>(xb, rowp, eidx, aggb);
        k_lin<1><<<gemm_grid, 256, 0, stream>>>(
            aggb, Wt + (size_t)l * D * D, b1 + (size_t)l * D,
            stats + (size_t)l * 256, nullptr, nullptr, zb);
        k_lin<2><<<gemm_grid, 256, 0, stream>>>(
            zb, Wt + (size_t)(NL + l) * D * D, b2 + (size_t)l * D,
            stats + (size_t)l * 256, gamma + (size_t)l * D, beta + (size_t)l * D, xb);
    }

    k_bounds<<<5, 256, 0, stream>>>(batch, dflag, starts);
    k_pool<<<N_GRAPHS, 128, 0, stream>>>(xb, starts, gp);
    k_head<<<N_GRAPHS, 128, 0, stream>>>(gp, fW1, fb1, fW2, fb2, out);
}